// Round 1
// baseline (1185.823 us; speedup 1.0000x reference)
//
#include <hip/hip_runtime.h>
#include <cmath>

// ---------------------------------------------------------------------------
// Problem constants (B=2, N=2048, C=1024, H=16, hd=64)
// ---------------------------------------------------------------------------
#define C_DIM   1024
#define H_DIM   16
#define HD      64
#define QKV_LD  3072   // 3*C row stride of qkv buffer

// ---------------------------------------------------------------------------
// Generic NT GEMM: C[m,n] = sum_k A[m,k]*B[n,k] (+bias[n])
// A: [M,K] row-major, B: [N,K] row-major. M,N multiples of 64, K multiple of 16.
// 64x64 tile, 256 threads, 4x4 per-thread micro-tile.
// ---------------------------------------------------------------------------
#define GBM 64
#define GBN 64
#define GBK 16
#define GPAD 68   // padded LDS leading dim: 68*4B = 272B, 16B-aligned, breaks 64-stride banks

__global__ __launch_bounds__(256) void gemm_nt(const float* __restrict__ A,
                                               const float* __restrict__ Bm,
                                               const float* __restrict__ bias,
                                               float* __restrict__ Cc,
                                               int M, int N, int K) {
  __shared__ __align__(16) float As[GBK][GPAD];
  __shared__ __align__(16) float Bs[GBK][GPAD];
  const int tid = threadIdx.x;
  const int tx = tid & 15, ty = tid >> 4;
  const int bm = blockIdx.y * GBM, bn = blockIdx.x * GBN;
  const int lr = tid >> 2;          // row within tile 0..63
  const int lk = (tid & 3) << 2;    // k offset 0,4,8,12
  const float* Ap = A  + (size_t)(bm + lr) * K + lk;
  const float* Bp = Bm + (size_t)(bn + lr) * K + lk;
  float acc[4][4] = {};
  for (int k0 = 0; k0 < K; k0 += GBK) {
    const float4 av = *(const float4*)(Ap + k0);
    const float4 bv = *(const float4*)(Bp + k0);
    As[lk+0][lr]=av.x; As[lk+1][lr]=av.y; As[lk+2][lr]=av.z; As[lk+3][lr]=av.w;
    Bs[lk+0][lr]=bv.x; Bs[lk+1][lr]=bv.y; Bs[lk+2][lr]=bv.z; Bs[lk+3][lr]=bv.w;
    __syncthreads();
#pragma unroll
    for (int kk = 0; kk < GBK; ++kk) {
      const float4 a = *(const float4*)&As[kk][ty << 2];
      const float4 b = *(const float4*)&Bs[kk][tx << 2];
      const float ar[4] = {a.x, a.y, a.z, a.w};
      const float br[4] = {b.x, b.y, b.z, b.w};
#pragma unroll
      for (int i = 0; i < 4; ++i)
#pragma unroll
        for (int j = 0; j < 4; ++j) acc[i][j] = fmaf(ar[i], br[j], acc[i][j]);
    }
    __syncthreads();
  }
#pragma unroll
  for (int i = 0; i < 4; ++i) {
    const int m = bm + (ty << 2) + i;
    float4 o;
    o.x = acc[i][0]; o.y = acc[i][1]; o.z = acc[i][2]; o.w = acc[i][3];
    if (bias) {
      o.x += bias[bn + (tx << 2) + 0];
      o.y += bias[bn + (tx << 2) + 1];
      o.z += bias[bn + (tx << 2) + 2];
      o.w += bias[bn + (tx << 2) + 3];
    }
    *(float4*)(Cc + (size_t)m * N + bn + (tx << 2)) = o;
  }
}

// ---------------------------------------------------------------------------
// In-place L2 normalize of q and k rows (hd=64 -> one wave per row).
// Row id r -> (bn, e, h): r = ((bn*2 + e)*16 + h), e=0 (q) / 1 (k).
// ---------------------------------------------------------------------------
__global__ void l2norm_qk(float* __restrict__ qkv) {
  const int gw   = (blockIdx.x * blockDim.x + threadIdx.x) >> 6;
  const int lane = threadIdx.x & 63;
  const int h  = gw & 15;
  const int e  = (gw >> 4) & 1;
  const int bn = gw >> 5;
  float* p = qkv + (size_t)bn * QKV_LD + e * C_DIM + h * HD + lane;
  const float v = *p;
  float ss = v * v;
#pragma unroll
  for (int off = 32; off; off >>= 1) ss += __shfl_xor(ss, off, 64);
  *p = v / (sqrtf(ss) + 1e-8f);
}

// ---------------------------------------------------------------------------
// Flash-style attention, fp32. One block = one (b,h) x 64-query tile.
// Score: S[i][j] = (q_i . k_j) * 0.125 * s_j ; masked entries set to 0 (NOT -inf,
// matching the reference's multiplicative mask before softmax).
// LDS: Qs [d][q], KPs [d][k] (reused as P [k][q]), Vs [k][d], stride 68.
// ---------------------------------------------------------------------------
#define SP 68

__global__ __launch_bounds__(256) void attn_kernel(const float* __restrict__ qkv,
                                                   const float* __restrict__ score,
                                                   const int* __restrict__ use_mask_p,
                                                   float* __restrict__ obuf,
                                                   int Ntok) {
  __shared__ __align__(16) float Qs[HD][SP];
  __shared__ __align__(16) float KPs[HD][SP];
  __shared__ __align__(16) float Vs[HD][SP];
  __shared__ float sjs[64];
  __shared__ float sis[64];
  const int tid = threadIdx.x;
  const int tx = tid & 15, ty = tid >> 4;
  const int q0 = blockIdx.x * 64;
  const int h  = blockIdx.y & 15;
  const int b  = blockIdx.y >> 4;
  const int umask = *use_mask_p;
  const int lr = tid >> 2;          // row 0..63
  const int d0 = (tid & 3) << 4;    // dim group base 0,16,32,48

  // ---- load Q tile (already L2-normalized) transposed into Qs[d][q] ----
  {
    const float* qp = qkv + (size_t)(b * Ntok + q0 + lr) * QKV_LD + h * HD + d0;
#pragma unroll
    for (int g = 0; g < 4; ++g) {
      const float4 v = *(const float4*)(qp + g * 4);
      Qs[d0 + g*4 + 0][lr] = v.x; Qs[d0 + g*4 + 1][lr] = v.y;
      Qs[d0 + g*4 + 2][lr] = v.z; Qs[d0 + g*4 + 3][lr] = v.w;
    }
    if (tid < 64) sis[tid] = score[q0 + tid];
  }

  float m_i[4], l_i[4], O[4][4];
#pragma unroll
  for (int i = 0; i < 4; ++i) {
    m_i[i] = -INFINITY; l_i[i] = 0.f;
#pragma unroll
    for (int j = 0; j < 4; ++j) O[i][j] = 0.f;
  }

  for (int k0 = 0; k0 < Ntok; k0 += 64) {
    __syncthreads();   // protect LDS against previous iteration's readers
    // ---- stage K (transposed) and V (row-major) ----
    {
      const float* kp = qkv + (size_t)(b * Ntok + k0 + lr) * QKV_LD + C_DIM + h * HD + d0;
#pragma unroll
      for (int g = 0; g < 4; ++g) {
        const float4 kv = *(const float4*)(kp + g * 4);
        KPs[d0 + g*4 + 0][lr] = kv.x; KPs[d0 + g*4 + 1][lr] = kv.y;
        KPs[d0 + g*4 + 2][lr] = kv.z; KPs[d0 + g*4 + 3][lr] = kv.w;
        const float4 vv = *(const float4*)(kp + C_DIM + g * 4);
        *(float4*)&Vs[lr][d0 + g * 4] = vv;
      }
      if (tid < 64) sjs[tid] = score[k0 + tid];
    }
    __syncthreads();

    // ---- S = Q K^T (4x4 per thread) ----
    float S[4][4] = {};
#pragma unroll 16
    for (int d = 0; d < HD; ++d) {
      const float4 a  = *(const float4*)&Qs[d][ty << 2];
      const float4 bv = *(const float4*)&KPs[d][tx << 2];
      const float ar[4] = {a.x, a.y, a.z, a.w};
      const float br[4] = {bv.x, bv.y, bv.z, bv.w};
#pragma unroll
      for (int i = 0; i < 4; ++i)
#pragma unroll
        for (int j = 0; j < 4; ++j) S[i][j] = fmaf(ar[i], br[j], S[i][j]);
    }

    // ---- scale * s_j, mask, online softmax update ----
    float sjv[4], siv[4];
#pragma unroll
    for (int j = 0; j < 4; ++j) sjv[j] = sjs[(tx << 2) + j];
#pragma unroll
    for (int i = 0; i < 4; ++i) siv[i] = sis[(ty << 2) + i];
    float P[4][4];
#pragma unroll
    for (int i = 0; i < 4; ++i) {
#pragma unroll
      for (int j = 0; j < 4; ++j) {
        float val = (S[i][j] * 0.125f) * sjv[j];
        if (umask && !(sjv[j] > siv[i] - 0.1f)) val = 0.f;
        S[i][j] = val;
      }
      float rm = fmaxf(fmaxf(S[i][0], S[i][1]), fmaxf(S[i][2], S[i][3]));
      rm = fmaxf(rm, __shfl_xor(rm, 1, 64));
      rm = fmaxf(rm, __shfl_xor(rm, 2, 64));
      rm = fmaxf(rm, __shfl_xor(rm, 4, 64));
      rm = fmaxf(rm, __shfl_xor(rm, 8, 64));
      const float mnew = fmaxf(m_i[i], rm);                 // rm is finite -> mnew finite
      const float alpha = __expf(m_i[i] - mnew);            // first iter: exp(-inf)=0
      float rs = 0.f;
#pragma unroll
      for (int j = 0; j < 4; ++j) { P[i][j] = __expf(S[i][j] - mnew); rs += P[i][j]; }
      rs += __shfl_xor(rs, 1, 64);
      rs += __shfl_xor(rs, 2, 64);
      rs += __shfl_xor(rs, 4, 64);
      rs += __shfl_xor(rs, 8, 64);
      l_i[i] = l_i[i] * alpha + rs;
      m_i[i] = mnew;
#pragma unroll
      for (int j = 0; j < 4; ++j) O[i][j] *= alpha;
    }

    __syncthreads();   // all S reads of KPs done
    // ---- write P into KPs as [k][q] ----
#pragma unroll
    for (int j = 0; j < 4; ++j)
#pragma unroll
      for (int i = 0; i < 4; ++i)
        KPs[(tx << 2) + j][(ty << 2) + i] = P[i][j];
    __syncthreads();

    // ---- O += P @ V ----
#pragma unroll 16
    for (int kk = 0; kk < 64; ++kk) {
      const float4 a  = *(const float4*)&KPs[kk][ty << 2];
      const float4 bv = *(const float4*)&Vs[kk][tx << 2];
      const float ar[4] = {a.x, a.y, a.z, a.w};
      const float br[4] = {bv.x, bv.y, bv.z, bv.w};
#pragma unroll
      for (int i = 0; i < 4; ++i)
#pragma unroll
        for (int j = 0; j < 4; ++j) O[i][j] = fmaf(ar[i], br[j], O[i][j]);
    }
  }

  // ---- epilogue: divide by softmax denom, write [B*N, C] layout ----
#pragma unroll
  for (int i = 0; i < 4; ++i) {
    const float inv = 1.0f / l_i[i];
    float4 o;
    o.x = O[i][0] * inv; o.y = O[i][1] * inv;
    o.z = O[i][2] * inv; o.w = O[i][3] * inv;
    *(float4*)(obuf + (size_t)(b * Ntok + q0 + (ty << 2) + i) * C_DIM + h * HD + (tx << 2)) = o;
  }
}

// ---------------------------------------------------------------------------
extern "C" void kernel_launch(void* const* d_in, const int* in_sizes, int n_in,
                              void* d_out, int out_size, void* d_ws, size_t ws_size,
                              hipStream_t stream) {
  const float* x       = (const float*)d_in[0];
  const float* score   = (const float*)d_in[1];
  const float* qkv_w   = (const float*)d_in[2];
  const float* proj_w  = (const float*)d_in[3];
  const float* proj_b  = (const float*)d_in[4];
  const int*   use_msk = (const int*)d_in[5];
  float* out = (float*)d_out;

  const int N = in_sizes[1];                 // 2048
  const int B = in_sizes[0] / (N * C_DIM);   // 2
  const int M = B * N;                       // 4096

  float* qkv  = (float*)d_ws;                          // [M, 3072]  48 MB
  float* obuf = qkv + (size_t)M * QKV_LD;              // [M, 1024]  16 MB

  // 1) QKV projection: [M,1024] x [3072,1024]^T -> [M,3072]
  {
    dim3 grid(3 * C_DIM / GBN, M / GBM);
    gemm_nt<<<grid, 256, 0, stream>>>(x, qkv_w, nullptr, qkv, M, 3 * C_DIM, C_DIM);
  }
  // 2) L2-normalize q,k rows in-place (M*2*H waves)
  {
    const int rows = M * 2 * H_DIM;
    l2norm_qk<<<rows * 64 / 256, 256, 0, stream>>>(qkv);
  }
  // 3) attention
  {
    dim3 grid(N / 64, B * H_DIM);
    attn_kernel<<<grid, 256, 0, stream>>>(qkv, score, use_msk, obuf, N);
  }
  // 4) output projection + bias: [M,1024] x [1024,1024]^T -> [M,1024]
  {
    dim3 grid(C_DIM / GBN, M / GBM);
    gemm_nt<<<grid, 256, 0, stream>>>(obuf, proj_w, proj_b, out, M, C_DIM, C_DIM);
  }
}

// Round 2
// 606.478 us; speedup vs baseline: 1.9553x; 1.9553x over previous
//
#include <hip/hip_runtime.h>
#include <cmath>

#define C_DIM   1024
#define H_DIM   16
#define HD      64
#define N_TOK   2048

typedef __attribute__((ext_vector_type(8))) short bf16x8;
typedef __attribute__((ext_vector_type(4))) float f32x4;

// round-to-nearest-even fp32 -> bf16
__device__ __forceinline__ unsigned short f2bf(float x) {
  union { float f; unsigned int u; } c; c.f = x;
  unsigned int r = (c.u + 0x7FFFu + ((c.u >> 16) & 1u)) >> 16;
  return (unsigned short)r;
}

// ---------------------------------------------------------------------------
// fp32 NT GEMM (proj): C[m,n] = sum_k A[m,k]*B[n,k] + bias[n]
// ---------------------------------------------------------------------------
#define GBM 64
#define GBN 64
#define GBK 16
#define GPAD 68

__global__ __launch_bounds__(256) void gemm_nt(const float* __restrict__ A,
                                               const float* __restrict__ Bm,
                                               const float* __restrict__ bias,
                                               float* __restrict__ Cc,
                                               int M, int N, int K) {
  __shared__ __align__(16) float As[GBK][GPAD];
  __shared__ __align__(16) float Bs[GBK][GPAD];
  const int tid = threadIdx.x;
  const int tx = tid & 15, ty = tid >> 4;
  const int bm = blockIdx.y * GBM, bn = blockIdx.x * GBN;
  const int lr = tid >> 2;
  const int lk = (tid & 3) << 2;
  const float* Ap = A  + (size_t)(bm + lr) * K + lk;
  const float* Bp = Bm + (size_t)(bn + lr) * K + lk;
  float acc[4][4] = {};
  for (int k0 = 0; k0 < K; k0 += GBK) {
    const float4 av = *(const float4*)(Ap + k0);
    const float4 bv = *(const float4*)(Bp + k0);
    As[lk+0][lr]=av.x; As[lk+1][lr]=av.y; As[lk+2][lr]=av.z; As[lk+3][lr]=av.w;
    Bs[lk+0][lr]=bv.x; Bs[lk+1][lr]=bv.y; Bs[lk+2][lr]=bv.z; Bs[lk+3][lr]=bv.w;
    __syncthreads();
#pragma unroll
    for (int kk = 0; kk < GBK; ++kk) {
      const float4 a = *(const float4*)&As[kk][ty << 2];
      const float4 b = *(const float4*)&Bs[kk][tx << 2];
      const float ar[4] = {a.x, a.y, a.z, a.w};
      const float br[4] = {b.x, b.y, b.z, b.w};
#pragma unroll
      for (int i = 0; i < 4; ++i)
#pragma unroll
        for (int j = 0; j < 4; ++j) acc[i][j] = fmaf(ar[i], br[j], acc[i][j]);
    }
    __syncthreads();
  }
#pragma unroll
  for (int i = 0; i < 4; ++i) {
    const int m = bm + (ty << 2) + i;
    float4 o;
    o.x = acc[i][0]; o.y = acc[i][1]; o.z = acc[i][2]; o.w = acc[i][3];
    if (bias) {
      o.x += bias[bn + (tx << 2) + 0];
      o.y += bias[bn + (tx << 2) + 1];
      o.z += bias[bn + (tx << 2) + 2];
      o.w += bias[bn + (tx << 2) + 3];
    }
    *(float4*)(Cc + (size_t)m * N + bn + (tx << 2)) = o;
  }
}

// ---------------------------------------------------------------------------
// QKV GEMM (fp32 compute) with fused epilogue:
//   mode 0 (cols 0..1023):    q -> L2-normalize per head-row -> bf16 qb[B,H,N,64]
//   mode 1 (cols 1024..2047): k -> L2-normalize -> bf16 kb[B,H,N,64]
//   mode 2 (cols 2048..3071): v -> bf16, transposed -> vbt[B,H,64,N]
// Each 64-col tile is exactly one head's 64 dims (tiles are 64-aligned).
// ---------------------------------------------------------------------------
__global__ __launch_bounds__(256) void gemm_qkv_fused(const float* __restrict__ A,
                                                      const float* __restrict__ Bm,
                                                      unsigned short* __restrict__ qb,
                                                      unsigned short* __restrict__ kb,
                                                      unsigned short* __restrict__ vbt,
                                                      int M, int K) {
  __shared__ __align__(16) float smem[2 * GBK * GPAD];   // 8704 B
  float* As = smem;
  float* Bs = smem + GBK * GPAD;
  const int tid = threadIdx.x;
  const int tx = tid & 15, ty = tid >> 4;
  const int bm = blockIdx.y * GBM, bn = blockIdx.x * GBN;
  const int lr = tid >> 2;
  const int lk = (tid & 3) << 2;
  const float* Ap = A  + (size_t)(bm + lr) * K + lk;
  const float* Bp = Bm + (size_t)(bn + lr) * K + lk;
  float acc[4][4] = {};
  for (int k0 = 0; k0 < K; k0 += GBK) {
    const float4 av = *(const float4*)(Ap + k0);
    const float4 bv = *(const float4*)(Bp + k0);
    As[(lk+0)*1 + 0]; // no-op to keep layout explicit below
    As[(lk+0)*GPAD? 0:0]; // (never executed wrong path; see direct writes)
    // direct staged writes:
    ((float*)As)[(lk+0)*GPAD + lr] = av.x;
    ((float*)As)[(lk+1)*GPAD + lr] = av.y;
    ((float*)As)[(lk+2)*GPAD + lr] = av.z;
    ((float*)As)[(lk+3)*GPAD + lr] = av.w;
    ((float*)Bs)[(lk+0)*GPAD + lr] = bv.x;
    ((float*)Bs)[(lk+1)*GPAD + lr] = bv.y;
    ((float*)Bs)[(lk+2)*GPAD + lr] = bv.z;
    ((float*)Bs)[(lk+3)*GPAD + lr] = bv.w;
    __syncthreads();
#pragma unroll
    for (int kk = 0; kk < GBK; ++kk) {
      const float4 a = *(const float4*)&As[kk*GPAD + (ty << 2)];
      const float4 b = *(const float4*)&Bs[kk*GPAD + (tx << 2)];
      const float ar[4] = {a.x, a.y, a.z, a.w};
      const float br[4] = {b.x, b.y, b.z, b.w};
#pragma unroll
      for (int i = 0; i < 4; ++i)
#pragma unroll
        for (int j = 0; j < 4; ++j) acc[i][j] = fmaf(ar[i], br[j], acc[i][j]);
    }
    __syncthreads();
  }

  const int mode = bn >> 10;          // 0=q, 1=k, 2=v
  const int h    = (bn >> 6) & 15;

  if (mode <= 1) {
    unsigned short* dst = mode ? kb : qb;
#pragma unroll
    for (int i = 0; i < 4; ++i) {
      const int m = bm + (ty << 2) + i;
      const int b = m >> 11, n = m & (N_TOK - 1);
      float ss = acc[i][0]*acc[i][0] + acc[i][1]*acc[i][1]
               + acc[i][2]*acc[i][2] + acc[i][3]*acc[i][3];
      ss += __shfl_xor(ss, 1, 64);
      ss += __shfl_xor(ss, 2, 64);
      ss += __shfl_xor(ss, 4, 64);
      ss += __shfl_xor(ss, 8, 64);
      const float sc = 1.0f / (sqrtf(ss) + 1e-8f);
      ushort4 o;
      o.x = f2bf(acc[i][0] * sc); o.y = f2bf(acc[i][1] * sc);
      o.z = f2bf(acc[i][2] * sc); o.w = f2bf(acc[i][3] * sc);
      *(ushort4*)(dst + ((size_t)(b * H_DIM + h) * N_TOK + n) * HD + (tx << 2)) = o;
    }
  } else {
    // transpose tile through LDS: Tb[d][token-in-tile], stride 68 bf16
    unsigned short* Tb = (unsigned short*)smem;   // needs 64*68*2 = 8704 B, exact fit
#pragma unroll
    for (int i = 0; i < 4; ++i)
#pragma unroll
      for (int j = 0; j < 4; ++j)
        Tb[((tx << 2) + j) * GPAD + (ty << 2) + i] = f2bf(acc[i][j]);
    __syncthreads();
    const int d = tid >> 2, c = (tid & 3) << 4;      // d row 0..63, 16 tokens
    const int b = bm >> 11, n0 = bm & (N_TOK - 1);
    unsigned int buf[8];
#pragma unroll
    for (int kk = 0; kk < 8; ++kk)
      buf[kk] = *(const unsigned int*)&Tb[d * GPAD + c + (kk << 1)];
    unsigned short* dst = vbt + ((size_t)(b * H_DIM + h) * HD + d) * N_TOK + n0 + c;
    *(uint4*)(dst)     = make_uint4(buf[0], buf[1], buf[2], buf[3]);
    *(uint4*)(dst + 8) = make_uint4(buf[4], buf[5], buf[6], buf[7]);
  }
}

// ---------------------------------------------------------------------------
// MFMA attention. Block = 4 waves = one 64-query tile of one (b,h).
// Wave w owns query rows [w*16, w*16+16). Per 64-key tile:
//   S (16x64) = Q K^T via 8 mfma_f32_16x16x32_bf16; softmax (no max-subtract:
//   |logit| <= 0.13); P -> LDS bf16; O += P V via 8 MFMAs.
// C-frag layout: col = lane&15, row = (lane>>4)*4 + reg.
// A/B-frag layout: [idx = lane&15][k = (lane>>4)*8 + j].
// ---------------------------------------------------------------------------
__global__ __launch_bounds__(256) void attn_mfma(const unsigned short* __restrict__ qb,
                                                 const unsigned short* __restrict__ kb,
                                                 const unsigned short* __restrict__ vbt,
                                                 const float* __restrict__ score,
                                                 const int* __restrict__ usem,
                                                 float* __restrict__ obuf) {
  __shared__ __align__(16) unsigned short Ks[64][72];
  __shared__ __align__(16) unsigned short Vt[64][72];
  __shared__ __align__(16) unsigned short Ps[4][16][72];
  __shared__ float sscl[64];
  __shared__ float sraw[64];

  const int tid  = threadIdx.x;
  const int w    = tid >> 6;
  const int lane = tid & 63;
  const int ln   = lane & 15;
  const int quad = lane >> 4;
  const int q0 = blockIdx.x * 64;
  const int bh = blockIdx.y;
  const int b  = bh >> 4, h = bh & 15;
  const int umask = *usem;

  // Q A-frags (held in registers for whole kernel)
  const unsigned short* qp = qb + ((size_t)bh * N_TOK + q0 + w * 16 + ln) * HD + quad * 8;
  const bf16x8 a0 = *(const bf16x8*)(qp);
  const bf16x8 a1 = *(const bf16x8*)(qp + 32);

  float si[4];
#pragma unroll
  for (int r = 0; r < 4; ++r) si[r] = score[q0 + w * 16 + quad * 4 + r];

  f32x4 O[4];
  float l[4];
#pragma unroll
  for (int t = 0; t < 4; ++t) { O[t] = (f32x4){0.f,0.f,0.f,0.f}; l[t] = 0.f; }

  const int sr = tid >> 2, sc = (tid & 3) << 4;
  const unsigned short* kbase = kb  + ((size_t)bh * N_TOK + sr) * HD + sc;
  const unsigned short* vbase = vbt + ((size_t)bh * HD + sr) * N_TOK + sc;

  for (int k0 = 0; k0 < N_TOK; k0 += 64) {
    __syncthreads();
    *(float4*)&Ks[sr][sc]     = *(const float4*)(kbase + (size_t)k0 * HD);
    *(float4*)&Ks[sr][sc + 8] = *(const float4*)(kbase + (size_t)k0 * HD + 8);
    *(float4*)&Vt[sr][sc]     = *(const float4*)(vbase + k0);
    *(float4*)&Vt[sr][sc + 8] = *(const float4*)(vbase + k0 + 8);
    if (tid < 64) { const float s = score[k0 + tid]; sraw[tid] = s; sscl[tid] = 0.125f * s; }
    __syncthreads();

    // ---- S = Q K^T ----
    f32x4 S[4];
#pragma unroll
    for (int t = 0; t < 4; ++t) {
      const bf16x8 b0 = *(const bf16x8*)&Ks[t * 16 + ln][quad * 8];
      const bf16x8 b1 = *(const bf16x8*)&Ks[t * 16 + ln][32 + quad * 8];
      f32x4 c = (f32x4){0.f,0.f,0.f,0.f};
      c = __builtin_amdgcn_mfma_f32_16x16x32_bf16(a0, b0, c, 0, 0, 0);
      c = __builtin_amdgcn_mfma_f32_16x16x32_bf16(a1, b1, c, 0, 0, 0);
      S[t] = c;
    }

    // ---- softmax terms (no max subtraction; masked -> exp(0)=1) ----
#pragma unroll
    for (int t = 0; t < 4; ++t) {
      const float sjs = sscl[t * 16 + ln];
      const float sjr = sraw[t * 16 + ln];
#pragma unroll
      for (int r = 0; r < 4; ++r) {
        float val = S[t][r] * sjs;
        if (umask && !(sjr > si[r] - 0.1f)) val = 0.f;
        const float p = __expf(val);
        l[r] += p;
        Ps[w][quad * 4 + r][t * 16 + ln] = f2bf(p);
      }
    }
    // Ps region is wave-private; compiler emits lgkmcnt waits for the RAW dep.

    // ---- O += P V ----
    const bf16x8 ap0 = *(const bf16x8*)&Ps[w][ln][quad * 8];
    const bf16x8 ap1 = *(const bf16x8*)&Ps[w][ln][32 + quad * 8];
#pragma unroll
    for (int t2 = 0; t2 < 4; ++t2) {
      const bf16x8 bv0 = *(const bf16x8*)&Vt[t2 * 16 + ln][quad * 8];
      const bf16x8 bv1 = *(const bf16x8*)&Vt[t2 * 16 + ln][32 + quad * 8];
      O[t2] = __builtin_amdgcn_mfma_f32_16x16x32_bf16(ap0, bv0, O[t2], 0, 0, 0);
      O[t2] = __builtin_amdgcn_mfma_f32_16x16x32_bf16(ap1, bv1, O[t2], 0, 0, 0);
    }
  }

  // ---- epilogue: reduce softmax denominators across the 16-lane col groups ----
  float inv[4];
#pragma unroll
  for (int r = 0; r < 4; ++r) {
    float s = l[r];
    s += __shfl_xor(s, 1, 64);
    s += __shfl_xor(s, 2, 64);
    s += __shfl_xor(s, 4, 64);
    s += __shfl_xor(s, 8, 64);
    inv[r] = 1.0f / s;
  }
#pragma unroll
  for (int t2 = 0; t2 < 4; ++t2)
#pragma unroll
    for (int r = 0; r < 4; ++r)
      obuf[((size_t)b * N_TOK + q0 + w * 16 + quad * 4 + r) * C_DIM + h * HD + t2 * 16 + ln]
        = O[t2][r] * inv[r];
}

// ---------------------------------------------------------------------------
extern "C" void kernel_launch(void* const* d_in, const int* in_sizes, int n_in,
                              void* d_out, int out_size, void* d_ws, size_t ws_size,
                              hipStream_t stream) {
  const float* x      = (const float*)d_in[0];
  const float* score  = (const float*)d_in[1];
  const float* qkv_w  = (const float*)d_in[2];
  const float* proj_w = (const float*)d_in[3];
  const float* proj_b = (const float*)d_in[4];
  const int*   usem   = (const int*)d_in[5];
  float* out = (float*)d_out;

  const int M = 2 * N_TOK;   // 4096 tokens

  // workspace: qb/kb/vbt bf16 (8 MiB each) + obuf fp32 (16 MiB) = 40 MiB
  unsigned short* qb  = (unsigned short*)d_ws;
  unsigned short* kb  = qb  + (size_t)M * C_DIM;   // 4194304 elems
  unsigned short* vbt = kb  + (size_t)M * C_DIM;
  float* obuf = (float*)(vbt + (size_t)M * C_DIM);

  // 1) QKV projection (fp32 VALU) + fused norm/pack/transpose epilogue
  {
    dim3 grid(3 * C_DIM / GBN, M / GBM);
    gemm_qkv_fused<<<grid, 256, 0, stream>>>(x, qkv_w, qb, kb, vbt, M, C_DIM);
  }
  // 2) MFMA attention
  {
    dim3 grid(N_TOK / 64, 2 * H_DIM);
    attn_mfma<<<grid, 256, 0, stream>>>(qb, kb, vbt, score, usem, obuf);
  }
  // 3) output projection + bias (fp32 VALU)
  {
    dim3 grid(C_DIM / GBN, M / GBM);
    gemm_nt<<<grid, 256, 0, stream>>>(obuf, proj_w, proj_b, out, M, C_DIM, C_DIM);
  }
}

// Round 3
// 243.842 us; speedup vs baseline: 4.8631x; 2.4872x over previous
//
#include <hip/hip_runtime.h>
#include <cmath>

#define C_DIM   1024
#define H_DIM   16
#define HD      64
#define N_TOK   2048
#define M_TOK   4096
#define LOG2E   1.44269504088896340736f

typedef _Float16 f16;
typedef __attribute__((ext_vector_type(8))) _Float16 f16x8;
typedef __attribute__((ext_vector_type(4))) float    f32x4;

// async global->LDS, 16B per lane; LDS dest = wave-uniform base + lane*16
__device__ __forceinline__ void gl_lds16(const void* g, void* l) {
  __builtin_amdgcn_global_load_lds((const __attribute__((address_space(1))) void*)g,
                                   (__attribute__((address_space(3))) void*)l, 16, 0, 0);
}

// ---------------------------------------------------------------------------
// fp32 -> fp16 convert: x (4.19M), qkv_w (3.15M), proj_w (1.05M), float4/thread
// ---------------------------------------------------------------------------
#define CVT_X4 1048576
#define CVT_W4 786432
#define CVT_P4 262144
__global__ __launch_bounds__(256) void cvt_all(const float* __restrict__ x,
                                               const float* __restrict__ w1,
                                               const float* __restrict__ w2,
                                               f16* __restrict__ xh,
                                               f16* __restrict__ wh1,
                                               f16* __restrict__ wh2) {
  const int i = blockIdx.x * 256 + threadIdx.x;
  const float4* src; f16* dst; int off;
  if (i < CVT_X4)               { src = (const float4*)x;  dst = xh;  off = i; }
  else if (i < CVT_X4 + CVT_W4) { src = (const float4*)w1; dst = wh1; off = i - CVT_X4; }
  else                          { src = (const float4*)w2; dst = wh2; off = i - CVT_X4 - CVT_W4; }
  const float4 v = src[off];
  union { f16 h[4]; ushort4 u; } p;
  p.h[0] = (f16)v.x; p.h[1] = (f16)v.y; p.h[2] = (f16)v.z; p.h[3] = (f16)v.w;
  *(ushort4*)(dst + (size_t)off * 4) = p.u;
}

// ---------------------------------------------------------------------------
// Shared MFMA NT-GEMM mainloop: 128x128 tile, BK=32, 4 waves (2x2), fp16.
// C[m,n] = sum_k A[m,k]*B[n,k]; A,B row-major fp16, lda=ldb=K.
// Per K-iter/wave: 4 global_load_lds(16B), 8 ds_read_b128, 16 MFMA.
// ---------------------------------------------------------------------------
__device__ __forceinline__ void gemm_mainloop(const f16* __restrict__ A,
                                              const f16* __restrict__ B,
                                              int K, int bm, int bn,
                                              f16* As, f16* Bs,
                                              f32x4 (&acc)[4][4]) {
  const int tid  = threadIdx.x;
  const int w    = tid >> 6, lane = tid & 63;
  const int wm   = w >> 1,   wn   = w & 1;
  const int ln   = lane & 15, quad = lane >> 4;
  const int sr   = lane >> 2;          // row within 16-row chunk
  const int sc   = (lane & 3) << 3;    // k offset in halves (0,8,16,24)

  const f16* Ag0 = A + (size_t)(bm + w * 16 + sr) * K + sc;
  const f16* Ag1 = A + (size_t)(bm + (w + 4) * 16 + sr) * K + sc;
  const f16* Bg0 = B + (size_t)(bn + w * 16 + sr) * K + sc;
  const f16* Bg1 = B + (size_t)(bn + (w + 4) * 16 + sr) * K + sc;
  f16* Al0 = As + (w * 16) * 32;       // wave-uniform LDS bases
  f16* Al1 = As + ((w + 4) * 16) * 32;
  f16* Bl0 = Bs + (w * 16) * 32;
  f16* Bl1 = Bs + ((w + 4) * 16) * 32;

  for (int k0 = 0; k0 < K; k0 += 32) {
    __syncthreads();
    gl_lds16(Ag0 + k0, Al0);
    gl_lds16(Ag1 + k0, Al1);
    gl_lds16(Bg0 + k0, Bl0);
    gl_lds16(Bg1 + k0, Bl1);
    __syncthreads();
    f16x8 af[4], bf[4];
#pragma unroll
    for (int fm = 0; fm < 4; ++fm)
      af[fm] = *(const f16x8*)&As[(wm * 64 + fm * 16 + ln) * 32 + quad * 8];
#pragma unroll
    for (int fn = 0; fn < 4; ++fn)
      bf[fn] = *(const f16x8*)&Bs[(wn * 64 + fn * 16 + ln) * 32 + quad * 8];
#pragma unroll
    for (int fm = 0; fm < 4; ++fm)
#pragma unroll
      for (int fn = 0; fn < 4; ++fn)
        acc[fm][fn] = __builtin_amdgcn_mfma_f32_16x16x32_f16(af[fm], bf[fn], acc[fm][fn], 0, 0, 0);
  }
}

// ---------------------------------------------------------------------------
// QKV GEMM + fused epilogue:
//   cols 0..1023    : q -> L2-normalize -> fp16 qb[B,H,N,64]
//   cols 1024..2047 : k -> L2-normalize * (0.125*log2e*score[n]) -> kb[B,H,N,64]
//   cols 2048..3071 : v -> fp16 transposed -> vt[B,H,64,N]
// C-frag: row m = quad*4+reg, col n = lane&15 (verified R1/R2).
// ---------------------------------------------------------------------------
__global__ __launch_bounds__(256) void gemm_qkv(const f16* __restrict__ A,
                                                const f16* __restrict__ B,
                                                const float* __restrict__ score,
                                                f16* __restrict__ qb,
                                                f16* __restrict__ kb,
                                                f16* __restrict__ vt) {
  __shared__ __align__(16) union {
    struct { f16 As[128 * 32]; f16 Bs[128 * 32]; } s;  // 16 KB mainloop
    f16 vtx[4][64][72];                                 // 36.9 KB v-transpose
  } sm;
  f32x4 acc[4][4];
#pragma unroll
  for (int i = 0; i < 4; ++i)
#pragma unroll
    for (int j = 0; j < 4; ++j) acc[i][j] = (f32x4){0.f, 0.f, 0.f, 0.f};

  const int bm = blockIdx.y * 128, bn = blockIdx.x * 128;
  gemm_mainloop(A, B, C_DIM, bm, bn, sm.s.As, sm.s.Bs, acc);

  const int tid = threadIdx.x;
  const int w = tid >> 6, lane = tid & 63;
  const int wm = w >> 1, wn = w & 1;
  const int ln = lane & 15, quad = lane >> 4;
  const int col0 = bn + wn * 64;          // head-aligned 64-col group
  const int mode = col0 >> 10;            // 0=q 1=k 2=v (block-uniform)
  const int h    = (col0 >> 6) & 15;

  if (mode <= 1) {
    f16* dst = mode ? kb : qb;
#pragma unroll
    for (int fm = 0; fm < 4; ++fm) {
#pragma unroll
      for (int r = 0; r < 4; ++r) {
        const int m = bm + wm * 64 + fm * 16 + quad * 4 + r;
        const int b = m >> 11, n = m & (N_TOK - 1);
        float ss = acc[fm][0][r] * acc[fm][0][r] + acc[fm][1][r] * acc[fm][1][r]
                 + acc[fm][2][r] * acc[fm][2][r] + acc[fm][3][r] * acc[fm][3][r];
        ss += __shfl_xor(ss, 1, 64);
        ss += __shfl_xor(ss, 2, 64);
        ss += __shfl_xor(ss, 4, 64);
        ss += __shfl_xor(ss, 8, 64);
        float sc = 1.0f / (sqrtf(ss) + 1e-8f);
        if (mode) sc *= 0.125f * LOG2E * score[n];
        f16* drow = dst + (((size_t)(b * H_DIM + h) * N_TOK + n) << 6);
#pragma unroll
        for (int fn = 0; fn < 4; ++fn)
          drow[fn * 16 + ln] = (f16)(acc[fm][fn][r] * sc);
      }
    }
  } else {
    __syncthreads();   // mainloop LDS -> transpose buffer (block-uniform branch)
#pragma unroll
    for (int fm = 0; fm < 4; ++fm)
#pragma unroll
      for (int fn = 0; fn < 4; ++fn)
#pragma unroll
        for (int r = 0; r < 4; ++r)
          sm.vtx[w][fn * 16 + ln][fm * 16 + quad * 4 + r] = (f16)acc[fm][fn][r];
    // wave-private region: in-wave lgkmcnt ordering suffices, no barrier
    const int m0 = bm + wm * 64;
    const int b = m0 >> 11, n0 = m0 & (N_TOK - 1);
    const int dg = lane >> 3;            // 0..7
    const int t8 = (lane & 7) << 3;      // 0..56
#pragma unroll
    for (int g = 0; g < 8; ++g) {
      const int d = g * 8 + dg;
      f16* drow = vt + (((size_t)(b * H_DIM + h) * HD + d) * N_TOK + n0 + t8);
      *(uint4*)drow = *(const uint4*)&sm.vtx[w][d][t8];
    }
  }
}

// ---------------------------------------------------------------------------
// Proj GEMM: out[m,n] = sum_k A[m,k]*B[n,k] + bias[n], fp32 out
// ---------------------------------------------------------------------------
__global__ __launch_bounds__(256) void gemm_proj(const f16* __restrict__ A,
                                                 const f16* __restrict__ B,
                                                 const float* __restrict__ bias,
                                                 float* __restrict__ out) {
  __shared__ __align__(16) struct { f16 As[128 * 32]; f16 Bs[128 * 32]; } sm;
  f32x4 acc[4][4];
#pragma unroll
  for (int i = 0; i < 4; ++i)
#pragma unroll
    for (int j = 0; j < 4; ++j) acc[i][j] = (f32x4){0.f, 0.f, 0.f, 0.f};

  const int bm = blockIdx.y * 128, bn = blockIdx.x * 128;
  gemm_mainloop(A, B, C_DIM, bm, bn, sm.As, sm.Bs, acc);

  const int tid = threadIdx.x;
  const int w = tid >> 6, lane = tid & 63;
  const int wm = w >> 1, wn = w & 1;
  const int ln = lane & 15, quad = lane >> 4;
  float bv[4];
#pragma unroll
  for (int fn = 0; fn < 4; ++fn) bv[fn] = bias[bn + wn * 64 + fn * 16 + ln];
#pragma unroll
  for (int fm = 0; fm < 4; ++fm)
#pragma unroll
    for (int r = 0; r < 4; ++r) {
      const int m = bm + wm * 64 + fm * 16 + quad * 4 + r;
#pragma unroll
      for (int fn = 0; fn < 4; ++fn)
        out[(size_t)m * C_DIM + bn + wn * 64 + fn * 16 + ln] = acc[fm][fn][r] + bv[fn];
    }
}

// ---------------------------------------------------------------------------
// MFMA attention (fp16). Block = 4 waves = 64-query tile of one (b,h).
// kb has 0.125*log2e*s_j folded in -> S is already log2-domain; p = exp2(S).
// Masked entries: S=0 -> p=1 (matches reference's multiplicative mask).
// ---------------------------------------------------------------------------
__global__ __launch_bounds__(256) void attn_mfma(const f16* __restrict__ qb,
                                                 const f16* __restrict__ kb,
                                                 const f16* __restrict__ vt,
                                                 const float* __restrict__ score,
                                                 const int* __restrict__ usem,
                                                 f16* __restrict__ obuf) {
  __shared__ __align__(16) f16 Ks[64][72];
  __shared__ __align__(16) f16 Vt[64][72];
  __shared__ __align__(16) f16 Ps[4][16][72];
  __shared__ float sraw[64];

  const int tid  = threadIdx.x;
  const int w    = tid >> 6;
  const int lane = tid & 63;
  const int ln   = lane & 15;
  const int quad = lane >> 4;
  const int q0 = blockIdx.x * 64;
  const int bh = blockIdx.y;
  const int b  = bh >> 4, h = bh & 15;
  const int umask = *usem;

  const f16* qp = qb + ((size_t)bh * N_TOK + q0 + w * 16 + ln) * HD + quad * 8;
  const f16x8 a0 = *(const f16x8*)(qp);
  const f16x8 a1 = *(const f16x8*)(qp + 32);

  float si[4];
#pragma unroll
  for (int r = 0; r < 4; ++r) si[r] = score[q0 + w * 16 + quad * 4 + r];

  f32x4 O[4];
  float l[4];
#pragma unroll
  for (int t = 0; t < 4; ++t) { O[t] = (f32x4){0.f, 0.f, 0.f, 0.f}; l[t] = 0.f; }

  const int sr = tid >> 2, sc = (tid & 3) << 4;
  const f16* kbase = kb + ((size_t)bh * N_TOK + sr) * HD + sc;
  const f16* vbase = vt + ((size_t)bh * HD + sr) * N_TOK + sc;

  for (int k0 = 0; k0 < N_TOK; k0 += 64) {
    __syncthreads();
    *(float4*)&Ks[sr][sc]     = *(const float4*)(kbase + (size_t)k0 * HD);
    *(float4*)&Ks[sr][sc + 8] = *(const float4*)(kbase + (size_t)k0 * HD + 8);
    *(float4*)&Vt[sr][sc]     = *(const float4*)(vbase + k0);
    *(float4*)&Vt[sr][sc + 8] = *(const float4*)(vbase + k0 + 8);
    if (tid < 64) sraw[tid] = score[k0 + tid];
    __syncthreads();

    // ---- S = Q K''^T (log2-domain logits) ----
    f32x4 S[4];
#pragma unroll
    for (int t = 0; t < 4; ++t) {
      const f16x8 b0 = *(const f16x8*)&Ks[t * 16 + ln][quad * 8];
      const f16x8 b1 = *(const f16x8*)&Ks[t * 16 + ln][32 + quad * 8];
      f32x4 c = (f32x4){0.f, 0.f, 0.f, 0.f};
      c = __builtin_amdgcn_mfma_f32_16x16x32_f16(a0, b0, c, 0, 0, 0);
      c = __builtin_amdgcn_mfma_f32_16x16x32_f16(a1, b1, c, 0, 0, 0);
      S[t] = c;
    }

    // ---- p = exp2(S); masked -> exp2(0) = 1 ----
#pragma unroll
    for (int t = 0; t < 4; ++t) {
      const float sjr = sraw[t * 16 + ln];
#pragma unroll
      for (int r = 0; r < 4; ++r) {
        float val = S[t][r];
        if (umask && !(sjr > si[r] - 0.1f)) val = 0.f;
        const float p = exp2f(val);
        l[r] += p;
        Ps[w][quad * 4 + r][t * 16 + ln] = (f16)p;
      }
    }

    // ---- O += P V ----
    const f16x8 ap0 = *(const f16x8*)&Ps[w][ln][quad * 8];
    const f16x8 ap1 = *(const f16x8*)&Ps[w][ln][32 + quad * 8];
#pragma unroll
    for (int t2 = 0; t2 < 4; ++t2) {
      const f16x8 bv0 = *(const f16x8*)&Vt[t2 * 16 + ln][quad * 8];
      const f16x8 bv1 = *(const f16x8*)&Vt[t2 * 16 + ln][32 + quad * 8];
      O[t2] = __builtin_amdgcn_mfma_f32_16x16x32_f16(ap0, bv0, O[t2], 0, 0, 0);
      O[t2] = __builtin_amdgcn_mfma_f32_16x16x32_f16(ap1, bv1, O[t2], 0, 0, 0);
    }
  }

  float inv[4];
#pragma unroll
  for (int r = 0; r < 4; ++r) {
    float s = l[r];
    s += __shfl_xor(s, 1, 64);
    s += __shfl_xor(s, 2, 64);
    s += __shfl_xor(s, 4, 64);
    s += __shfl_xor(s, 8, 64);
    inv[r] = 1.0f / s;
  }
#pragma unroll
  for (int t2 = 0; t2 < 4; ++t2)
#pragma unroll
    for (int r = 0; r < 4; ++r)
      obuf[((size_t)(b * N_TOK + q0 + w * 16 + quad * 4 + r)) * C_DIM + h * HD + t2 * 16 + ln]
        = (f16)(O[t2][r] * inv[r]);
}

// ---------------------------------------------------------------------------
extern "C" void kernel_launch(void* const* d_in, const int* in_sizes, int n_in,
                              void* d_out, int out_size, void* d_ws, size_t ws_size,
                              hipStream_t stream) {
  const float* x      = (const float*)d_in[0];
  const float* score  = (const float*)d_in[1];
  const float* qkv_w  = (const float*)d_in[2];
  const float* proj_w = (const float*)d_in[3];
  const float* proj_b = (const float*)d_in[4];
  const int*   usem   = (const int*)d_in[5];
  float* out = (float*)d_out;

  // workspace (halves): xh 4.19M, wh 3.15M, pwh 1.05M, qb/kb/vt/obuf 4.19M each = 48 MB
  f16* xh   = (f16*)d_ws;
  f16* wh   = xh  + (size_t)M_TOK * C_DIM;
  f16* pwh  = wh  + (size_t)3 * C_DIM * C_DIM;
  f16* qb   = pwh + (size_t)C_DIM * C_DIM;
  f16* kb   = qb  + (size_t)M_TOK * C_DIM;
  f16* vt   = kb  + (size_t)M_TOK * C_DIM;
  f16* obuf = vt  + (size_t)M_TOK * C_DIM;

  // 1) fp32 -> fp16 conversions
  cvt_all<<<(CVT_X4 + CVT_W4 + CVT_P4) / 256, 256, 0, stream>>>(x, qkv_w, proj_w, xh, wh, pwh);
  // 2) QKV projection (fp16 MFMA) + fused norm/fold/pack/transpose
  {
    dim3 grid(3 * C_DIM / 128, M_TOK / 128);
    gemm_qkv<<<grid, 256, 0, stream>>>(xh, wh, score, qb, kb, vt);
  }
  // 3) attention (fp16 MFMA)
  {
    dim3 grid(N_TOK / 64, 2 * H_DIM);
    attn_mfma<<<grid, 256, 0, stream>>>(qb, kb, vt, score, usem, obuf);
  }
  // 4) output projection + bias (fp16 MFMA, fp32 out)
  {
    dim3 grid(C_DIM / 128, M_TOK / 128);
    gemm_proj<<<grid, 256, 0, stream>>>(obuf, pwh, proj_b, out);
  }
}